// Round 1
// 111.863 us; speedup vs baseline: 1.0837x; 1.0837x over previous
//
#include <hip/hip_runtime.h>

#define S 512
#define H 128
#define NROW 4096   // B*S
#define TI 8

typedef _Float16 h2v __attribute__((ext_vector_type(2)));
#define BCH(x) __builtin_bit_cast(h2v, (x))

// ---------------- kernel 1: qp/kp projection (fp32 math, fp16x2 store) ----
// qp[row][h] = sum_d query[row][d]*W1[h][d] + b1[h]   -> qph half2-packed
// kp[row][h] = sum_d key[row][d]  *W1[h][128+d]       -> kph half2-packed
__global__ __launch_bounds__(256) void proj_kernel(
    const float* __restrict__ query, const float* __restrict__ key,
    const float* __restrict__ W1, const float* __restrict__ b1,
    const float* __restrict__ W2,
    unsigned* __restrict__ qph, unsigned* __restrict__ kph,
    unsigned* __restrict__ w2h)
{
  __shared__ float w1t[128][130];   // w1t[d][h] = W1[h][off+d]
  const int bid = blockIdx.x;       // 0..255
  const bool isq = bid < 128;
  const float* __restrict__ src = isq ? query : key;
  const int rbase = (isq ? bid : bid - 128) * 32;
  const int off = isq ? 0 : 128;
  const int tid = threadIdx.x;

  // pack W2 -> half2 once (block 0)
  if (bid == 0 && tid < 64) {
    h2v p;
    p.x = (_Float16)W2[2 * tid];
    p.y = (_Float16)W2[2 * tid + 1];
    w2h[tid] = __builtin_bit_cast(unsigned, p);
  }

  for (int idx = tid; idx < 128 * 32; idx += 256) {
    const int d4 = idx & 31, h = idx >> 5;
    const float4 v = *(const float4*)(W1 + h * 256 + off + d4 * 4);
    w1t[d4 * 4 + 0][h] = v.x;
    w1t[d4 * 4 + 1][h] = v.y;
    w1t[d4 * 4 + 2][h] = v.z;
    w1t[d4 * 4 + 3][h] = v.w;
  }
  __syncthreads();

  const int w = __builtin_amdgcn_readfirstlane(tid >> 6);
  const int lane = tid & 63;
  const int r0 = rbase + w * 8;

  float acc[8][2];
  float2 bv = make_float2(0.f, 0.f);
  if (isq) bv = *(const float2*)(b1 + 2 * lane);
  #pragma unroll
  for (int r = 0; r < 8; r++) { acc[r][0] = bv.x; acc[r][1] = bv.y; }

  for (int dc = 0; dc < 128; dc += 8) {
    float qs[8][8];                 // wave-uniform -> SGPRs via s_load
    #pragma unroll
    for (int r = 0; r < 8; r++) {
      const float* sp = src + (size_t)(r0 + r) * H + dc;
      #pragma unroll
      for (int u = 0; u < 8; u++) qs[r][u] = sp[u];
    }
    #pragma unroll
    for (int dd = 0; dd < 8; dd++) {
      const float2 wv = *(const float2*)&w1t[dc + dd][2 * lane];
      #pragma unroll
      for (int r = 0; r < 8; r++) {
        acc[r][0] = __builtin_fmaf(qs[r][dd], wv.x, acc[r][0]);
        acc[r][1] = __builtin_fmaf(qs[r][dd], wv.y, acc[r][1]);
      }
    }
  }
  unsigned* __restrict__ dst = isq ? qph : kph;
  #pragma unroll
  for (int r = 0; r < 8; r++) {
    h2v p;
    p.x = (_Float16)acc[r][0];      // h = 2*lane
    p.y = (_Float16)acc[r][1];      // h = 2*lane+1
    dst[(size_t)(r0 + r) * 64 + lane] = __builtin_bit_cast(unsigned, p);
  }
}

// ---------------- kernel 2: fused scores + exp + AV + normalize ----------
// grid: 512 blocks (one per (b, i-tile of 8 rows)), 512 threads = 8 waves.
// wave w owns j in [w*64, w*64+64); lane = local j. Full j-range in one
// block -> no partials, out written directly.
__global__ __launch_bounds__(512) void attn_kernel(
    const unsigned* __restrict__ qph, const unsigned* __restrict__ kph,
    const unsigned* __restrict__ w2h, const float* __restrict__ value,
    const int* __restrict__ q_mask, const int* __restrict__ k_mask,
    const float* __restrict__ b2, float* __restrict__ out)
{
  union __align__(16) SMU {
    float aT[8][64][12];            // per-wave a bounce (phase 2 input)
    float numk[8][TI][128];         // per-wave num partials (after barrier)
  };
  __shared__ SMU sm;
  __shared__ float denk[8][TI];

  const int it = blockIdx.x;        // 0..511
  const int r0 = it * TI;           // global q-row base (uniform)
  const int b = r0 >> 9;
  const int tid = threadIdx.x;
  const int w = __builtin_amdgcn_readfirstlane(tid >> 6);   // 0..7
  const int lane = tid & 63;
  const int jl = (w << 6) + lane;   // within-b key index 0..511
  const int jg = (b << 9) + jl;     // global key row
  const int km = k_mask[jg];
  const unsigned* __restrict__ kprow = kph + (size_t)jg * 64;
  const float b2v = b2[0];
  const h2v hz = {};

  // ---- phase 1: s[i] for this lane's j (packed fp16, fp32 accum) ----
  float s[TI];
  #pragma unroll
  for (int i = 0; i < TI; i++) s[i] = 0.f;

  for (int hc = 0; hc < 64; hc += 16) {   // 16 half2 = 32 h per chunk
    h2v kr[16];
    {
      const uint4* k4 = (const uint4*)(kprow + hc);
      const uint4 a0 = k4[0], a1 = k4[1], a2 = k4[2], a3 = k4[3];
      kr[0]  = BCH(a0.x); kr[1]  = BCH(a0.y); kr[2]  = BCH(a0.z); kr[3]  = BCH(a0.w);
      kr[4]  = BCH(a1.x); kr[5]  = BCH(a1.y); kr[6]  = BCH(a1.z); kr[7]  = BCH(a1.w);
      kr[8]  = BCH(a2.x); kr[9]  = BCH(a2.y); kr[10] = BCH(a2.z); kr[11] = BCH(a2.w);
      kr[12] = BCH(a3.x); kr[13] = BCH(a3.y); kr[14] = BCH(a3.z); kr[15] = BCH(a3.w);
    }
    h2v w2c[16];                    // uniform -> SGPRs
    #pragma unroll
    for (int u = 0; u < 16; u++) w2c[u] = BCH(w2h[hc + u]);

    #pragma unroll
    for (int i = 0; i < TI; i++) {
      const unsigned* __restrict__ qrow =
          qph + (size_t)(r0 + i) * 64 + hc;   // uniform -> s_load batch
      unsigned qu[16];
      #pragma unroll
      for (int u = 0; u < 16; u++) qu[u] = qrow[u];
      #pragma unroll
      for (int u = 0; u < 16; u++) {
        h2v t = BCH(qu[u]) + kr[u];                    // v_pk_add_f16
        t = __builtin_elementwise_max(t, hz);          // v_pk_max_f16
        s[i] = __builtin_amdgcn_fdot2(t, w2c[u], s[i], false); // v_dot2_f32_f16
      }
    }
  }

  // ---- mask + exp + intra-wave den reduce ----
  float a[TI];
  #pragma unroll
  for (int i = 0; i < TI; i++) {
    const int qm = q_mask[r0 + i];  // uniform
    a[i] = (km > 0 && qm > 0) ? __expf(s[i] + b2v) : 0.f;
  }
  #pragma unroll
  for (int i = 0; i < TI; i++) {
    float d = a[i];
    #pragma unroll
    for (int m = 32; m >= 1; m >>= 1) d += __shfl_xor(d, m, 64);
    if (lane == 0) denk[w][i] = d;
  }
  *(float4*)&sm.aT[w][lane][0] = make_float4(a[0], a[1], a[2], a[3]);
  *(float4*)&sm.aT[w][lane][4] = make_float4(a[4], a[5], a[6], a[7]);
  __syncthreads();   // aT visible; also orders vs union reuse below

  // ---- phase 2: num[i][h] += a[i][j]*v[j][h] over this wave's 64 j ----
  const int lj = lane >> 5, lh = lane & 31;   // lj: j-parity, lh*4: h window
  float nr[TI][4];
  #pragma unroll
  for (int i = 0; i < TI; i++) { nr[i][0]=0.f; nr[i][1]=0.f; nr[i][2]=0.f; nr[i][3]=0.f; }
  const float* __restrict__ vbase =
      value + ((size_t)b * S + (w << 6)) * H;

  for (int js = 0; js < 32; js++) {
    const int j = js * 2 + lj;
    const float4 vv = *(const float4*)(vbase + (size_t)j * H + lh * 4);
    float av[TI];
    { const float4 t0 = *(const float4*)&sm.aT[w][j][0];
      const float4 t1 = *(const float4*)&sm.aT[w][j][4];
      av[0]=t0.x; av[1]=t0.y; av[2]=t0.z; av[3]=t0.w;
      av[4]=t1.x; av[5]=t1.y; av[6]=t1.z; av[7]=t1.w; }
    #pragma unroll
    for (int i = 0; i < TI; i++) {
      nr[i][0] = __builtin_fmaf(av[i], vv.x, nr[i][0]);
      nr[i][1] = __builtin_fmaf(av[i], vv.y, nr[i][1]);
      nr[i][2] = __builtin_fmaf(av[i], vv.z, nr[i][2]);
      nr[i][3] = __builtin_fmaf(av[i], vv.w, nr[i][3]);
    }
  }
  #pragma unroll
  for (int i = 0; i < TI; i++) {
    #pragma unroll
    for (int k = 0; k < 4; k++) nr[i][k] += __shfl_xor(nr[i][k], 32, 64);
  }

  __syncthreads();   // everyone done reading aT before numk overwrites it
  if (lane < 32) {   // lh == lane; both j-parities hold the folded sum
    #pragma unroll
    for (int i = 0; i < TI; i++)
      *(float4*)&sm.numk[w][i][lane * 4] =
          make_float4(nr[i][0], nr[i][1], nr[i][2], nr[i][3]);
  }
  __syncthreads();

  // ---- cross-wave reduce + normalize + store (fused finalize) ----
  const int ii = tid >> 6;              // 0..7
  const int h0 = (tid & 63) * 2;        // 0,2,..,126
  float nx = 0.f, ny = 0.f, d = 0.f;
  #pragma unroll
  for (int ww = 0; ww < 8; ww++) {
    const float2 t = *(const float2*)&sm.numk[ww][ii][h0];
    nx += t.x; ny += t.y;
    d += denk[ww][ii];
  }
  const float inv = 1.f / fmaxf(d, 2e-15f);
  *(float2*)(out + (size_t)(r0 + ii) * H + h0) = make_float2(nx * inv, ny * inv);
}

extern "C" void kernel_launch(void* const* d_in, const int* in_sizes, int n_in,
                              void* d_out, int out_size, void* d_ws, size_t ws_size,
                              hipStream_t stream)
{
  (void)in_sizes; (void)n_in; (void)out_size; (void)ws_size;
  const float* query  = (const float*)d_in[0];
  const float* key    = (const float*)d_in[1];
  const float* value  = (const float*)d_in[2];
  const int*   q_mask = (const int*)d_in[3];
  const int*   k_mask = (const int*)d_in[4];
  const float* W1     = (const float*)d_in[5];
  const float* b1     = (const float*)d_in[6];
  const float* W2     = (const float*)d_in[7];
  const float* b2     = (const float*)d_in[8];
  float* out = (float*)d_out;

  unsigned* ws  = (unsigned*)d_ws;
  unsigned* qph = ws;                                // [4096][64] half2
  unsigned* kph = ws + (size_t)NROW * 64;            // [4096][64] half2
  unsigned* w2h = kph + (size_t)NROW * 64;           // [64] half2

  proj_kernel<<<256, 256, 0, stream>>>(query, key, W1, b1, W2, qph, kph, w2h);
  attn_kernel<<<512, 512, 0, stream>>>(qph, kph, w2h, value, q_mask, k_mask,
                                       b2, out);
}